// Round 10
// baseline (169.759 us; speedup 1.0000x reference)
//
#include <hip/hip_runtime.h>
#include <hip/hip_bf16.h>
#include <math.h>

// loss = (1/C) * sum_i log( sum_j exp(<x_i,x_j>/T) ),  x: [16384, 256] fp32, unit rows.
// R9: R8 skeleton (lower-triangle fi partition, ring-4 B buffers, A pinned in regs,
// fragment-major LDS, no atomics) restructured into the m201-style 4-phase-per-fi
// schedule: each phase {ds_read 8 bfrag | issue 1 gll16(fi+2) | barrier | setprio(1)
// 32 MFMA setprio(0) | exp2+sums | lgkmcnt(0) barrier}. Counted vmcnt(4) once per fi
// (phase 3) keeps 1 prefetch batch in flight across barriers. R6/R8 A/B showed pipes
// run serially (MfmaUtil31+VALU24+LDS23 ~ sum); per-phase interleave is the T3/T4 fix.

#define N_ROWS 16384
#define KD     256
#define NBLK   256                    // 1 block/CU
#define NSLOT  96                     // rowacc: 0..31 col-path(k=rb), 64..95 row-path

// exp(sim/T) = exp2( dot * (1/T)*log2 e ); sqrt folded into BOTH operands at convert.
#define SCALE_SQRT 1.6986436f

typedef short short8 __attribute__((ext_vector_type(8)));   // 8 bf16 = 4 VGPRs
typedef float f32x4  __attribute__((ext_vector_type(4)));

typedef __attribute__((address_space(3))) void       lds_void;
typedef const __attribute__((address_space(1))) void gm_void;

__device__ __forceinline__ float fast_exp2(float x) {
#if __has_builtin(__builtin_amdgcn_exp2f)
    return __builtin_amdgcn_exp2f(x);
#else
    return exp2f(x);
#endif
}

__device__ __forceinline__ void gll16(const void* g, void* l) {
    __builtin_amdgcn_global_load_lds((gm_void*)g, (lds_void*)l, 16, 0, 0);
}

// ---------------- fp32 -> bf16 (RNE, pre-scaled) + zero rowacc/out ----------------
__global__ void convert_kernel(const float* __restrict__ x, unsigned short* __restrict__ xb,
                               float* __restrict__ rowacc, float* __restrict__ out) {
    const int bx = blockIdx.x, tid = threadIdx.x;
    if (bx < (NSLOT * N_ROWS) / 1024)
        *(float4*)(rowacc + (size_t)(bx * 256 + tid) * 4) = (float4){0.f, 0.f, 0.f, 0.f};
    if (bx == 2000 && tid == 0) out[0] = 0.f;
    int i = (bx * 256 + tid) * 4;
    float4 v = *(const float4*)(x + i);
    ushort4 o;
    {
        unsigned int u;
        u = __float_as_uint(v.x * SCALE_SQRT); u += 0x7fff + ((u >> 16) & 1); o.x = (unsigned short)(u >> 16);
        u = __float_as_uint(v.y * SCALE_SQRT); u += 0x7fff + ((u >> 16) & 1); o.y = (unsigned short)(u >> 16);
        u = __float_as_uint(v.z * SCALE_SQRT); u += 0x7fff + ((u >> 16) & 1); o.z = (unsigned short)(u >> 16);
        u = __float_as_uint(v.w * SCALE_SQRT); u += 0x7fff + ((u >> 16) & 1); o.w = (unsigned short)(u >> 16);
    }
    *(ushort4*)(xb + i) = o;
}

// ---------------- main fused kernel ----------------
// 512 thr = 8 waves; wave w owns A rows [r0 + w*64, +64) (pinned). Band rb (512 rows,
// rb=0..31) has 8*(rb+1) fi of 64 cols; block b owns fi in [(b*33)>>1, ((b+1)*33)>>1).
// Ring-4 B buffers (32KB), depth-2 prefetch with counted vmcnt, 4 phases per fi.
__global__ __launch_bounds__(512, 2)
void simloss_main(const unsigned short* __restrict__ xb, float* __restrict__ rowacc) {
    __shared__ __align__(128) char smem[4 * 32768 + 2048 + 4096];
    float* const rowred = (float*)(smem + 131072);          // [512]
    float* const colred = (float*)(smem + 131072 + 2048);   // [2][8][64]

    const int tid  = threadIdx.x;
    const int lane = tid & 63;
    const int w    = tid >> 6;                  // 0..7
    const int l15  = lane & 15;
    const int lg   = lane >> 4;                 // 0..3
    const int b    = blockIdx.x;

    int f          = (b * 33) >> 1;             // 16.5 fi per block
    const int fEnd = ((b + 1) * 33) >> 1;
    const int rowSlot = 64 + (b & 31);          // blocks sharing a band span <=17 ids

    int rb = (int)((sqrtf((float)f + 1.f) - 1.f) * 0.5f);
    while (4 * (rb + 1) * (rb + 2) <= f) ++rb;
    while (4 * rb * (rb + 1) > f) --rb;

    #pragma unroll 1
    while (f < fEnd) {
        while (4 * (rb + 1) * (rb + 2) <= f) ++rb;          // advance band
        const int bandStart = 4 * rb * (rb + 1);
        const int cblk0   = f - bandStart;                  // first 64-col chunk
        const int bandEnd = bandStart + 8 * (rb + 1);
        const int lim = fEnd < bandEnd ? fEnd : bandEnd;
        const int NI  = lim - f;                            // fi in this segment
        const int r0  = rb * 512;

        // stage one gll16 (g=0..3) of fi-batch into ring buffer
        auto stageG = [&](int buf, int cblk, int g) {
            const int fr = w * 4 + g;                       // frag 0..31: ct=fr>>3, kt=fr&7
            const int ct = fr >> 3, kt = fr & 7;
            const unsigned short* s =
                xb + (size_t)(cblk * 64 + ct * 16 + l15) * KD + kt * 32 + lg * 8;
            gll16(s, smem + buf * 32768 + fr * 1024);
        };

        // prologue: stage fi=0 (and fi=1), load+pin A, drain, barrier
        #pragma unroll
        for (int g = 0; g < 4; ++g) stageG(0, cblk0, g);
        if (NI > 1) {
            #pragma unroll
            for (int g = 0; g < 4; ++g) stageG(1, cblk0 + 1, g);
        }

        short8 afrag[4][8];                                 // A: row=lane&15, k=kt*32+lg*8+j
        #pragma unroll
        for (int m = 0; m < 4; ++m) {
            const unsigned short* ar = xb + (size_t)(r0 + w * 64 + m * 16 + l15) * KD + lg * 8;
            #pragma unroll
            for (int kt = 0; kt < 8; ++kt)
                afrag[m][kt] = *(const short8*)(ar + kt * 32);
        }
        #pragma unroll
        for (int m = 0; m < 4; ++m)
            #pragma unroll
            for (int kt = 0; kt < 8; ++kt)
                asm volatile("" : "+v"(afrag[m][kt]));      // pin (rolled fi-loop -> AGPRs)

        asm volatile("s_waitcnt vmcnt(0)" ::: "memory");
        __builtin_amdgcn_s_barrier();

        float rowsum[4][4] = {{0.f}};

        #pragma unroll 1                                    // MUST stay rolled (R4 lesson)
        for (int fi = 0; fi < NI; ++fi) {
            const char* bbase = smem + (fi & 3) * 32768;
            float* cw = colred + (fi & 1) * 512;

            #pragma unroll
            for (int p = 0; p < 4; ++p) {
                // --- pre-barrier: ds_read this phase's 8 B-frags (lane-linear, 0-conflict)
                short8 bfrag[8];
                #pragma unroll
                for (int kt = 0; kt < 8; ++kt)
                    bfrag[kt] = *(const short8*)(bbase + (p * 8 + kt) * 1024 + lane * 16);
                // --- issue one prefetch load for fi+2
                if (fi + 2 < NI) stageG((fi + 2) & 3, cblk0 + fi + 2, p);
                // --- phase 0: flush previous fi's col-sums (unique-writer slot k=rb)
                if (p == 0 && fi > 0 && tid < 64) {
                    const int pc = cblk0 + fi - 1;
                    if (pc < rb * 8) {                      // strictly below diagonal band
                        const float* cp = colred + ((fi - 1) & 1) * 512;
                        float cs = 0.f;
                        #pragma unroll
                        for (int w2 = 0; w2 < 8; ++w2) cs += cp[w2 * 64 + tid];
                        rowacc[(size_t)rb * N_ROWS + pc * 64 + tid] = cs;
                    }
                }
                // --- counted vmcnt once per fi (phase 3): fi+1 landed, fi+2 in flight
                if (p == 3) {
                    if (fi + 2 < NI) { asm volatile("s_waitcnt vmcnt(4)" ::: "memory"); }
                    else             { asm volatile("s_waitcnt vmcnt(0)" ::: "memory"); }
                }
                __builtin_amdgcn_sched_barrier(0);
                __builtin_amdgcn_s_barrier();
                __builtin_amdgcn_sched_barrier(0);

                // --- MFMA cluster (kt outer: 4 indep acc chains)
                __builtin_amdgcn_s_setprio(1);
                f32x4 acc[4];
                #pragma unroll
                for (int m = 0; m < 4; ++m) acc[m] = (f32x4){0.f, 0.f, 0.f, 0.f};
                #pragma unroll
                for (int kt = 0; kt < 8; ++kt)
                    #pragma unroll
                    for (int m = 0; m < 4; ++m)
                        acc[m] = __builtin_amdgcn_mfma_f32_16x16x32_bf16(afrag[m][kt], bfrag[kt], acc[m], 0, 0, 0);
                __builtin_amdgcn_s_setprio(0);

                // --- exp2 + row partials + tree col-sum (4 parallel chains)
                // C/D: col = lane&15, row-in-16 = (lane>>4)*4 + r
                float c0 = 0.f, c1 = 0.f, c2 = 0.f, c3 = 0.f;
                #pragma unroll
                for (int m = 0; m < 4; ++m) {
                    float e0 = fast_exp2(acc[m][0]); rowsum[m][0] += e0; c0 += e0;
                    float e1 = fast_exp2(acc[m][1]); rowsum[m][1] += e1; c1 += e1;
                    float e2 = fast_exp2(acc[m][2]); rowsum[m][2] += e2; c2 += e2;
                    float e3 = fast_exp2(acc[m][3]); rowsum[m][3] += e3; c3 += e3;
                }
                float csum = (c0 + c1) + (c2 + c3);
                csum += __shfl_xor(csum, 16);               // sum wave's 64 rows per col
                csum += __shfl_xor(csum, 32);
                if (lg == 0) cw[w * 64 + p * 16 + l15] = csum;

                asm volatile("s_waitcnt lgkmcnt(0)" ::: "memory");
                __builtin_amdgcn_sched_barrier(0);
                __builtin_amdgcn_s_barrier();
            }
        }

        __syncthreads();                                    // segment end

        if (tid < 64) {                                     // flush last fi's col-sums
            const int pc = cblk0 + NI - 1;
            if (pc < rb * 8) {
                const float* cp = colred + ((NI - 1) & 1) * 512;
                float cs = 0.f;
                #pragma unroll
                for (int w2 = 0; w2 < 8; ++w2) cs += cp[w2 * 64 + tid];
                rowacc[(size_t)rb * N_ROWS + pc * 64 + tid] = cs;
            }
        }

        // row-sums: reduce over 16 col-lanes -> rowred -> coalesced store
        #pragma unroll
        for (int m = 0; m < 4; ++m)
            #pragma unroll
            for (int r = 0; r < 4; ++r) {
                float v = rowsum[m][r];
                v += __shfl_xor(v, 1);
                v += __shfl_xor(v, 2);
                v += __shfl_xor(v, 4);
                v += __shfl_xor(v, 8);
                if (l15 == 0) rowred[w * 64 + m * 16 + lg * 4 + r] = v;
            }
        __syncthreads();
        rowacc[(size_t)rowSlot * N_ROWS + r0 + tid] = rowred[tid];

        f = lim;
    }
}

// ---------------- finalize: loss = sum_i log( sum_k rowacc[k][i] ) / 100 ----------------
__global__ void finalize_kernel(const float* __restrict__ rowacc, float* __restrict__ out) {
    int i = blockIdx.x * 256 + threadIdx.x;
    float s = 0.f;
    #pragma unroll 8
    for (int k = 0; k < NSLOT; ++k) s += rowacc[(size_t)k * N_ROWS + i];
    float v = logf(s);
    #pragma unroll
    for (int off = 1; off < 64; off <<= 1) v += __shfl_xor(v, off);
    __shared__ float red[4];
    if ((threadIdx.x & 63) == 0) red[threadIdx.x >> 6] = v;
    __syncthreads();
    if (threadIdx.x == 0)
        atomicAdd(out, (red[0] + red[1] + red[2] + red[3]) * 0.01f);
}

extern "C" void kernel_launch(void* const* d_in, const int* in_sizes, int n_in,
                              void* d_out, int out_size, void* d_ws, size_t ws_size,
                              hipStream_t stream) {
    const float* x = (const float*)d_in[0];
    unsigned short* xb = (unsigned short*)d_ws;                           // 8 MB bf16 (pre-scaled)
    float* rowacc = (float*)((char*)d_ws + (size_t)N_ROWS * KD * 2);      // 96 x 16384 f32 (6 MB)
    float* out = (float*)d_out;

    convert_kernel<<<(N_ROWS * KD) / (256 * 4), 256, 0, stream>>>(x, xb, rowacc, out);
    simloss_main<<<NBLK, 512, 0, stream>>>(xb, rowacc);
    finalize_kernel<<<N_ROWS / 256, 256, 0, stream>>>(rowacc, out);
}

// Round 11
// 155.571 us; speedup vs baseline: 1.0912x; 1.0912x over previous
//
#include <hip/hip_runtime.h>
#include <hip/hip_bf16.h>
#include <math.h>

// loss = (1/C) * sum_i log( sum_j exp(<x_i,x_j>/T) ),  x: [16384, 256] fp32, unit rows.
// R10: R8 skeleton (lower-triangle fi partition, ring-4 B buffers, A pinned, fragment-
// major LDS, 1 barrier/fi, no atomics) + T15 deferred epilogue: two acc sets alternate
// per ct-phase; phase P's MFMAs issue into `cur` while the PREVIOUS phase's acc gets its
// exp2/rowsum/csum — breaking the acc->exp2 dependency that serialized MFMA and VALU
// pipes (R6/R8/R9 all ~31% MfmaUtil; MfmaUtil+VALU+LDS ~ sum => serial pipes).
// colred is triple-buffered (ct3-piece lands one fi late); flush shifted to fi-2.

#define N_ROWS 16384
#define KD     256
#define NBLK   256                    // 1 block/CU
#define NSLOT  96                     // rowacc: 0..31 col-path(k=rb), 64..95 row-path

// exp(sim/T) = exp2( dot * (1/T)*log2 e ); sqrt folded into BOTH operands at convert.
#define SCALE_SQRT 1.6986436f

typedef short short8 __attribute__((ext_vector_type(8)));   // 8 bf16 = 4 VGPRs
typedef float f32x4  __attribute__((ext_vector_type(4)));

typedef __attribute__((address_space(3))) void       lds_void;
typedef const __attribute__((address_space(1))) void gm_void;

__device__ __forceinline__ float fast_exp2(float x) {
#if __has_builtin(__builtin_amdgcn_exp2f)
    return __builtin_amdgcn_exp2f(x);
#else
    return exp2f(x);
#endif
}

__device__ __forceinline__ void gll16(const void* g, void* l) {
    __builtin_amdgcn_global_load_lds((gm_void*)g, (lds_void*)l, 16, 0, 0);
}

// ---------------- fp32 -> bf16 (RNE, pre-scaled) + zero rowacc/out ----------------
__global__ void convert_kernel(const float* __restrict__ x, unsigned short* __restrict__ xb,
                               float* __restrict__ rowacc, float* __restrict__ out) {
    const int bx = blockIdx.x, tid = threadIdx.x;
    if (bx < (NSLOT * N_ROWS) / 1024)
        *(float4*)(rowacc + (size_t)(bx * 256 + tid) * 4) = (float4){0.f, 0.f, 0.f, 0.f};
    if (bx == 2000 && tid == 0) out[0] = 0.f;
    int i = (bx * 256 + tid) * 4;
    float4 v = *(const float4*)(x + i);
    ushort4 o;
    {
        unsigned int u;
        u = __float_as_uint(v.x * SCALE_SQRT); u += 0x7fff + ((u >> 16) & 1); o.x = (unsigned short)(u >> 16);
        u = __float_as_uint(v.y * SCALE_SQRT); u += 0x7fff + ((u >> 16) & 1); o.y = (unsigned short)(u >> 16);
        u = __float_as_uint(v.z * SCALE_SQRT); u += 0x7fff + ((u >> 16) & 1); o.z = (unsigned short)(u >> 16);
        u = __float_as_uint(v.w * SCALE_SQRT); u += 0x7fff + ((u >> 16) & 1); o.w = (unsigned short)(u >> 16);
    }
    *(ushort4*)(xb + i) = o;
}

// process a finished acc set: exp2 + rowsum accumulate + col-sum tree + colred write
#define PROC_PREV(ACCP, CWP, PSLOT)                                            \
  {                                                                            \
    float c0 = 0.f, c1 = 0.f, c2 = 0.f, c3 = 0.f;                              \
    _Pragma("unroll")                                                          \
    for (int m = 0; m < 4; ++m) {                                              \
      float e0 = fast_exp2(ACCP[m][0]); rowsum[m][0] += e0; c0 += e0;          \
      float e1 = fast_exp2(ACCP[m][1]); rowsum[m][1] += e1; c1 += e1;          \
      float e2 = fast_exp2(ACCP[m][2]); rowsum[m][2] += e2; c2 += e2;          \
      float e3 = fast_exp2(ACCP[m][3]); rowsum[m][3] += e3; c3 += e3;          \
    }                                                                          \
    float csum_ = (c0 + c1) + (c2 + c3);                                       \
    csum_ += __shfl_xor(csum_, 16);                                            \
    csum_ += __shfl_xor(csum_, 32);                                            \
    if (lg == 0) (CWP)[w * 64 + (PSLOT) * 16 + l15] = csum_;                   \
  }

// one ct-phase: read 8 B-frags (4+4 to cap live regs), 32 MFMAs into ACCC,
// then process the PREVIOUS phase's ACCP (overlaps this phase's MFMA drain).
#define PHASE(P, ACCC, ACCP, PSLOT, CWP, DOPREV)                               \
  {                                                                            \
    short8 bfA[4], bfB[4];                                                     \
    _Pragma("unroll")                                                          \
    for (int kt = 0; kt < 4; ++kt)                                             \
      bfA[kt] = *(const short8*)(bbase + ((P) * 8 + kt) * 1024 + lane * 16);   \
    _Pragma("unroll")                                                          \
    for (int m = 0; m < 4; ++m) ACCC[m] = (f32x4){0.f, 0.f, 0.f, 0.f};         \
    _Pragma("unroll")                                                          \
    for (int kt = 0; kt < 4; ++kt)                                             \
      _Pragma("unroll")                                                        \
      for (int m = 0; m < 4; ++m)                                              \
        ACCC[m] = __builtin_amdgcn_mfma_f32_16x16x32_bf16(afrag[m][kt], bfA[kt], ACCC[m], 0, 0, 0); \
    _Pragma("unroll")                                                          \
    for (int kt = 0; kt < 4; ++kt)                                             \
      bfB[kt] = *(const short8*)(bbase + ((P) * 8 + 4 + kt) * 1024 + lane * 16); \
    _Pragma("unroll")                                                          \
    for (int kt = 0; kt < 4; ++kt)                                             \
      _Pragma("unroll")                                                        \
      for (int m = 0; m < 4; ++m)                                              \
        ACCC[m] = __builtin_amdgcn_mfma_f32_16x16x32_bf16(afrag[m][4 + kt], bfB[kt], ACCC[m], 0, 0, 0); \
    if (DOPREV) PROC_PREV(ACCP, CWP, PSLOT)                                    \
  }

// ---------------- main fused kernel ----------------
// 512 thr = 8 waves; wave w owns A rows [r0 + w*64, +64) (pinned). Band rb (512 rows,
// rb=0..31) has 8*(rb+1) fi of 64 cols; block b owns fi in [(b*33)>>1, ((b+1)*33)>>1).
__global__ __launch_bounds__(512, 2)
void simloss_main(const unsigned short* __restrict__ xb, float* __restrict__ rowacc) {
    __shared__ __align__(128) char smem[4 * 32768 + 2048 + 3 * 2048];
    float* const rowred = (float*)(smem + 131072);          // [512]
    float* const colred = (float*)(smem + 131072 + 2048);   // [3][8][64] triple buffer

    const int tid  = threadIdx.x;
    const int lane = tid & 63;
    const int w    = tid >> 6;                  // 0..7
    const int l15  = lane & 15;
    const int lg   = lane >> 4;                 // 0..3
    const int b    = blockIdx.x;

    int f          = (b * 33) >> 1;             // 16.5 fi per block
    const int fEnd = ((b + 1) * 33) >> 1;
    const int rowSlot = 64 + (b & 31);          // blocks sharing a band span <=17 ids

    int rb = (int)((sqrtf((float)f + 1.f) - 1.f) * 0.5f);
    while (4 * (rb + 1) * (rb + 2) <= f) ++rb;
    while (4 * rb * (rb + 1) > f) --rb;

    #pragma unroll 1
    while (f < fEnd) {
        while (4 * (rb + 1) * (rb + 2) <= f) ++rb;          // advance band
        const int bandStart = 4 * rb * (rb + 1);
        const int cblk0   = f - bandStart;                  // first 64-col chunk
        const int bandEnd = bandStart + 8 * (rb + 1);
        const int lim = fEnd < bandEnd ? fEnd : bandEnd;
        const int NI  = lim - f;                            // fi in this segment
        const int r0  = rb * 512;

        auto stageB = [&](int buf, int cblk) {
            #pragma unroll
            for (int g = 0; g < 4; ++g) {
                const int fr = w * 4 + g;                   // frag 0..31: ct=fr>>3, kt=fr&7
                const int ct = fr >> 3, kt = fr & 7;
                const unsigned short* s =
                    xb + (size_t)(cblk * 64 + ct * 16 + l15) * KD + kt * 32 + lg * 8;
                gll16(s, smem + buf * 32768 + fr * 1024);
            }
        };
        stageB(0, cblk0);                                   // depth-2 prologue
        if (NI > 1) stageB(1, cblk0 + 1);

        short8 afrag[4][8];                                 // A: row=lane&15, k=kt*32+lg*8+j
        #pragma unroll
        for (int m = 0; m < 4; ++m) {
            const unsigned short* ar = xb + (size_t)(r0 + w * 64 + m * 16 + l15) * KD + lg * 8;
            #pragma unroll
            for (int kt = 0; kt < 8; ++kt)
                afrag[m][kt] = *(const short8*)(ar + kt * 32);
        }
        #pragma unroll
        for (int m = 0; m < 4; ++m)
            #pragma unroll
            for (int kt = 0; kt < 8; ++kt)
                asm volatile("" : "+v"(afrag[m][kt]));      // pin (rolled fi-loop -> AGPRs)

        float rowsum[4][4] = {{0.f}};
        f32x4 accA[4], accB[4];                             // alternating acc sets

        #pragma unroll 1                                    // MUST stay rolled (R4 lesson)
        for (int fi = 0; fi < NI; ++fi) {
            if (fi + 2 < NI) {
                stageB((fi + 2) & 3, cblk0 + fi + 2);
                asm volatile("s_waitcnt vmcnt(8)" ::: "memory");
            } else if (fi + 1 < NI) {
                asm volatile("s_waitcnt vmcnt(4)" ::: "memory");
            } else {
                asm volatile("s_waitcnt vmcnt(0)" ::: "memory");
            }
            asm volatile("s_waitcnt lgkmcnt(0)" ::: "memory");  // colred writes visible
            __builtin_amdgcn_s_barrier();                   // ONE barrier per fi
            asm volatile("" ::: "memory");

            // flush fi-2's col-sums (its last piece landed during fi-1's P0)
            if (fi >= 2 && tid < 64) {
                const int pc = cblk0 + fi - 2;
                if (pc < rb * 8) {                          // strictly below diagonal band
                    const float* cp = colred + ((fi - 2) % 3) * 512;
                    float cs = 0.f;
                    #pragma unroll
                    for (int w2 = 0; w2 < 8; ++w2) cs += cp[w2 * 64 + tid];
                    rowacc[(size_t)rb * N_ROWS + pc * 64 + tid] = cs;
                }
            }

            const char* bbase = smem + (fi & 3) * 32768;
            float* cwCur  = colred + (fi % 3) * 512;
            float* cwPrev = colred + ((fi + 2) % 3) * 512;  // == (fi-1)%3

            PHASE(0, accA, accB, 3, cwPrev, (fi > 0))       // process prev fi's ct3
            PHASE(1, accB, accA, 0, cwCur, 1)               // process ct0
            PHASE(2, accA, accB, 1, cwCur, 1)               // process ct1
            PHASE(3, accB, accA, 2, cwCur, 1)               // process ct2
            // accB now holds fi's ct3 (processed next fi / epilogue)
            asm volatile("" ::: "memory");
        }

        // ---- segment epilogue ----
        PROC_PREV(accB, colred + ((NI - 1) % 3) * 512, 3)   // last fi's ct3
        __syncthreads();                                    // all pieces + compute visible

        if (tid < 64) {                                     // flush remaining buffers
            if (NI >= 2) {
                const int pc = cblk0 + NI - 2;
                if (pc < rb * 8) {
                    const float* cp = colred + ((NI - 2) % 3) * 512;
                    float cs = 0.f;
                    #pragma unroll
                    for (int w2 = 0; w2 < 8; ++w2) cs += cp[w2 * 64 + tid];
                    rowacc[(size_t)rb * N_ROWS + pc * 64 + tid] = cs;
                }
            }
            {
                const int pc = cblk0 + NI - 1;
                if (pc < rb * 8) {
                    const float* cp = colred + ((NI - 1) % 3) * 512;
                    float cs = 0.f;
                    #pragma unroll
                    for (int w2 = 0; w2 < 8; ++w2) cs += cp[w2 * 64 + tid];
                    rowacc[(size_t)rb * N_ROWS + pc * 64 + tid] = cs;
                }
            }
        }

        // row-sums: reduce over 16 col-lanes -> rowred -> coalesced store
        #pragma unroll
        for (int m = 0; m < 4; ++m)
            #pragma unroll
            for (int r = 0; r < 4; ++r) {
                float v = rowsum[m][r];
                v += __shfl_xor(v, 1);
                v += __shfl_xor(v, 2);
                v += __shfl_xor(v, 4);
                v += __shfl_xor(v, 8);
                if (l15 == 0) rowred[w * 64 + m * 16 + lg * 4 + r] = v;
            }
        __syncthreads();
        rowacc[(size_t)rowSlot * N_ROWS + r0 + tid] = rowred[tid];

        f = lim;
    }
}

// ---------------- finalize: loss = sum_i log( sum_k rowacc[k][i] ) / 100 ----------------
__global__ void finalize_kernel(const float* __restrict__ rowacc, float* __restrict__ out) {
    int i = blockIdx.x * 256 + threadIdx.x;
    float s = 0.f;
    #pragma unroll 8
    for (int k = 0; k < NSLOT; ++k) s += rowacc[(size_t)k * N_ROWS + i];
    float v = logf(s);
    #pragma unroll
    for (int off = 1; off < 64; off <<= 1) v += __shfl_xor(v, off);
    __shared__ float red[4];
    if ((threadIdx.x & 63) == 0) red[threadIdx.x >> 6] = v;
    __syncthreads();
    if (threadIdx.x == 0)
        atomicAdd(out, (red[0] + red[1] + red[2] + red[3]) * 0.01f);
}

extern "C" void kernel_launch(void* const* d_in, const int* in_sizes, int n_in,
                              void* d_out, int out_size, void* d_ws, size_t ws_size,
                              hipStream_t stream) {
    const float* x = (const float*)d_in[0];
    unsigned short* xb = (unsigned short*)d_ws;                           // 8 MB bf16 (pre-scaled)
    float* rowacc = (float*)((char*)d_ws + (size_t)N_ROWS * KD * 2);      // 96 x 16384 f32 (6 MB)
    float* out = (float*)d_out;

    convert_kernel<<<(N_ROWS * KD) / (256 * 4), 256, 0, stream>>>(x, xb, rowacc, out);
    simloss_main<<<NBLK, 512, 0, stream>>>(xb, rowacc);
    finalize_kernel<<<N_ROWS / 256, 256, 0, stream>>>(rowacc, out);
}